// Round 8
// baseline (270.388 us; speedup 1.0000x reference)
//
#include <hip/hip_runtime.h>

#define MAXLEN 100
#define HDIM 64
#define CH 8                       // x-staging chunk length (steps)
#define SROW 72                    // ushorts per bf16 x step-row (144 B)
#define SPLANE (CH * SROW + 8)     // 584 ushorts per segment plane
#define HSTR 72                    // ushorts per h row (144 B)
#define L2E 1.44269504f

typedef __attribute__((ext_vector_type(8))) short bf16x8;
typedef __attribute__((ext_vector_type(4))) float f32x4;
typedef unsigned int u32;

// Step barrier: LDS-only consistency. Avoids the compiler's implicit
// s_waitcnt vmcnt(0) before s_barrier, so in-flight global_load_lds DMA
// is NOT drained at step barriers (only at the explicit chunk-boundary wait).
#define LGKM_BARRIER() asm volatile("s_waitcnt lgkmcnt(0)\n\ts_barrier" ::: "memory")
#define WAIT_VM0()     asm volatile("s_waitcnt vmcnt(0)" ::: "memory")

__device__ __forceinline__ void dma16(const float* g, u32* lds) {
    // 64 lanes x 16B -> contiguous 1 KB at wave-uniform LDS base (+lane*16).
    __builtin_amdgcn_global_load_lds((const __attribute__((address_space(1))) u32*)g,
                                     (__attribute__((address_space(3))) u32*)lds, 16, 0, 0);
}

__device__ __forceinline__ unsigned short f2bf_u(float f) {   // RNE f32->bf16
    unsigned u = __float_as_uint(f);
    u += 0x7fffu + ((u >> 16) & 1u);
    return (unsigned short)(u >> 16);
}
__device__ __forceinline__ unsigned pk2(float a, float b) {
    return (unsigned)f2bf_u(a) | ((unsigned)f2bf_u(b) << 16);
}
__device__ __forceinline__ bf16x8 pack8(f32x4 a, f32x4 b) {
    union { unsigned u[4]; bf16x8 v; } c;
    c.u[0] = pk2(a[0], a[1]); c.u[1] = pk2(a[2], a[3]);
    c.u[2] = pk2(b[0], b[1]); c.u[3] = pk2(b[2], b[3]);
    return c.v;
}
// sigmoid(v + b) with bs = -L2E*b folded into the exp2 argument.
__device__ __forceinline__ float sig_b(float v, float bs) {
    return __builtin_amdgcn_rcpf(1.0f + __builtin_amdgcn_exp2f(fmaf(v, -L2E, bs)));
}
__device__ __forceinline__ float tanh_b(float v, float bs2) {
    return fmaf(2.0f, __builtin_amdgcn_rcpf(1.0f + __builtin_amdgcn_exp2f(fmaf(v, -2.0f * L2E, bs2))), -1.0f);
}
__device__ __forceinline__ float tanh_p(float v) {
    return fmaf(2.0f, __builtin_amdgcn_rcpf(1.0f + __builtin_amdgcn_exp2f(v * (-2.0f * L2E))), -1.0f);
}

// 1024 blocks x 256 threads; 8 segments/block; 4 waves, wave w owns hidden
// cols [16w,16w+16) for all 4 gates. Segment s maps to MFMA A/C row
// (s>>1)*4 + (s&1): each lane's C regs 0..1 are its 2 real (seg,hid) bundles.
// x staged by chunk: global->LDS fp32 DMA (per-lane row-clamped addresses,
// zero VGPRs in flight) -> per-chunk bf16 convert pass -> step loop reads
// ready-made bf16 A-frags from LDS. Invariant: chunk k is in flight iff
// k < nch, and every issued DMA is vm-waited before kernel end (a dangling
// global_load_lds at s_endpgm would write into LDS reassigned to another
// block -> cross-block corruption; this was R7's bug, along with chunk-base
// clamping that shifted tail-segment rows).
__global__ __launch_bounds__(256, 4)
void lstm8_kernel(const float* __restrict__ x,
                  const float* __restrict__ Wih,
                  const float* __restrict__ Whh,
                  const float* __restrict__ bih,
                  const float* __restrict__ bhh,
                  const int* __restrict__ index,
                  float* __restrict__ out, int N, int B) {
    const int tid  = threadIdx.x;
    const int w    = tid >> 6;
    const int lane = tid & 63;
    const int l15  = lane & 15;
    const int quad = lane >> 4;
    const int segbase = blockIdx.x * 8;
    const int ncol = w * 16 + l15;

    __shared__ __align__(16) float xf32[8 * CH * HDIM];          // 16 KB DMA dest
    __shared__ __align__(16) unsigned short xst[9 * SPLANE];     // 10.5 KB (plane 8 = zeros)
    __shared__ __align__(16) unsigned short hst[2][16][HSTR];    // 4.6 KB
    __shared__ int sstart[8], slen[8];

    // --- per-block segment bounds (index sorted) ---
    if (tid < 8) {
        const int b = segbase + tid;
        int lo = 0, hi = N;
        while (lo < hi) { int m = (lo + hi) >> 1; if (index[m] < b) lo = m + 1; else hi = m; }
        const int s = lo;
        hi = N;
        while (lo < hi) { int m = (lo + hi) >> 1; if (index[m] < b + 1) lo = m + 1; else hi = m; }
        int len = lo - s;
        sstart[tid] = s;
        slen[tid] = len < MAXLEN ? len : MAXLEN;
    }
    for (int i = tid; i < 2 * 16 * HSTR / 2; i += 256) ((int*)hst)[i] = 0;
    for (int i = tid; i < SPLANE / 2; i += 256) ((int*)xst)[8 * SPLANE / 2 + i] = 0;
    __syncthreads();

    // --- weight B-fragments (register-resident) + exp-folded biases ---
    bf16x8 wi[4][2], wh[4][2];
    float bs[4];
#pragma unroll
    for (int g = 0; g < 4; ++g) {
        const int row = g * HDIM + ncol;
        const float bb = bih[row] + bhh[row];
        bs[g] = (g == 2) ? (-2.0f * L2E) * bb : (-L2E) * bb;
#pragma unroll
        for (int kt = 0; kt < 2; ++kt) {
            const f32x4* pi = (const f32x4*)(Wih + (size_t)row * HDIM + kt * 32 + quad * 8);
            const f32x4* ph = (const f32x4*)(Whh + (size_t)row * HDIM + kt * 32 + quad * 8);
            wi[g][kt] = pack8(pi[0], pi[1]);
            wh[g][kt] = pack8(ph[0], ph[1]);
        }
    }

    int len2[2];
    len2[0] = slen[2 * quad];
    len2[1] = slen[2 * quad + 1];
    int lmax = 0;
#pragma unroll
    for (int i = 0; i < 8; ++i) { int v = slen[i]; lmax = v > lmax ? v : lmax; }

    // DMA roles: wave w stages segs 2w, 2w+1 (2 KB each = 2 instrs of 4 rows).
    // Lane covers chunk-step (lane>>4) [+4 for the 2nd instr], col (lane&15)*4.
    // Global row per lane is exactly clamped to min(t, len-1) (frozen steps
    // re-read the last valid row; their gate output is discarded anyway).
    const int s0 = 2 * w, s1 = 2 * w + 1;
    const int st0 = sstart[s0], st1 = sstart[s1];
    const int sl0 = slen[s0],   sl1 = slen[s1];
    const int lrow = lane >> 4, lcol = (lane & 15) * 4;

#define CLAMPT(t_, sl_) ((sl_) > 0 ? ((t_) < (sl_) ? (t_) : (sl_) - 1) : 0)
#define CROW(st_, ct_)  ({ long long r_ = (long long)(st_) + (ct_);              \
                           r_ > (long long)(N - 1) ? (long long)(N - 1) : r_; })
#define DMA(t0_)                                                                 \
    {                                                                            \
        const int ta = (t0_) + lrow;                                             \
        long long rA0 = CROW(st0, CLAMPT(ta,     sl0));                          \
        long long rA1 = CROW(st0, CLAMPT(ta + 4, sl0));                          \
        long long rB0 = CROW(st1, CLAMPT(ta,     sl1));                          \
        long long rB1 = CROW(st1, CLAMPT(ta + 4, sl1));                          \
        dma16(x + rA0 * HDIM + lcol, (u32*)&xf32[s0 * CH * HDIM]);               \
        dma16(x + rA1 * HDIM + lcol, (u32*)&xf32[s0 * CH * HDIM + 4 * HDIM]);    \
        dma16(x + rB0 * HDIM + lcol, (u32*)&xf32[s1 * CH * HDIM]);               \
        dma16(x + rB1 * HDIM + lcol, (u32*)&xf32[s1 * CH * HDIM + 4 * HDIM]);    \
    }

    // Convert role: lane covers 16 floats of the wave's own 2 segments.
    const int cseg = 2 * w + (lane >> 5);
    const int crow = (lane >> 2) & 7;
    const int ccol = (lane & 3) * 16;
    const float* csrc = &xf32[(cseg * CH + crow) * HDIM + ccol];
    unsigned short* cdst = &xst[cseg * SPLANE + crow * SROW + ccol];

#define CONVERT()                                                                \
    {                                                                            \
        f32x4 a0 = *(const f32x4*)csrc;                                          \
        f32x4 a1 = *(const f32x4*)(csrc + 4);                                    \
        f32x4 a2 = *(const f32x4*)(csrc + 8);                                    \
        f32x4 a3 = *(const f32x4*)(csrc + 12);                                   \
        uint4 o1, o2;                                                            \
        o1.x = pk2(a0[0], a0[1]); o1.y = pk2(a0[2], a0[3]);                      \
        o1.z = pk2(a1[0], a1[1]); o1.w = pk2(a1[2], a1[3]);                      \
        o2.x = pk2(a2[0], a2[1]); o2.y = pk2(a2[2], a2[3]);                      \
        o2.z = pk2(a3[0], a3[1]); o2.w = pk2(a3[2], a3[3]);                      \
        *(uint4*)cdst = o1; *(uint4*)(cdst + 8) = o2;                            \
    }

    // x A-frag source plane for this lane's A-row: real seg or zero plane.
    const int xp = (l15 & 2) ? 8 : ((l15 >> 2) * 2 + (l15 & 1));
    const unsigned short* xb = &xst[xp * SPLANE + quad * 8];

    float c2[2] = {0, 0}, h2[2] = {0, 0};
    const f32x4 cz = {0.0f, 0.0f, 0.0f, 0.0f};
    const int nch = (lmax + CH - 1) / CH;

    if (nch > 0) {
        DMA(0);
        WAIT_VM0();
        CONVERT();
        LGKM_BARRIER();
        if (nch > 1) DMA(CH);          // chunk 1 in flight across chunk 0's steps

        for (int ch = 0; ch < nch; ++ch) {
            const int t0 = ch * CH;
#pragma unroll
            for (int tt = 0; tt < CH; ++tt) {
                const int t = t0 + tt;          // parity(t) == parity(tt)
                const int pb = tt & 1, nb = pb ^ 1;

                const unsigned short* xr = xb + tt * SROW;
                bf16x8 xa0 = *(const bf16x8*)(xr);
                bf16x8 xa1 = *(const bf16x8*)(xr + 32);
                const unsigned short* hr = &hst[pb][l15][quad * 8];
                bf16x8 ha0 = *(const bf16x8*)(hr);
                bf16x8 ha1 = *(const bf16x8*)(hr + 32);

                f32x4 acc[4];
#pragma unroll
                for (int g = 0; g < 4; ++g) {
                    f32x4 a = __builtin_amdgcn_mfma_f32_16x16x32_bf16(xa0, wi[g][0], cz, 0, 0, 0);
                    a = __builtin_amdgcn_mfma_f32_16x16x32_bf16(xa1, wi[g][1], a, 0, 0, 0);
                    a = __builtin_amdgcn_mfma_f32_16x16x32_bf16(ha0, wh[g][0], a, 0, 0, 0);
                    a = __builtin_amdgcn_mfma_f32_16x16x32_bf16(ha1, wh[g][1], a, 0, 0, 0);
                    acc[g] = a;
                }

                // Gate math: 2 real bundles/lane (C regs 0..1 = segs 2q, 2q+1).
#pragma unroll
                for (int r = 0; r < 2; ++r) {
                    float gi = sig_b (acc[0][r], bs[0]);
                    float gf = sig_b (acc[1][r], bs[1]);
                    float gg = tanh_b(acc[2][r], bs[2]);
                    float go = sig_b (acc[3][r], bs[3]);
                    float cn = fmaf(gf, c2[r], gi * gg);
                    float hn = go * tanh_p(cn);
                    const bool up = t < len2[r];
                    c2[r] = up ? cn : c2[r];
                    h2[r] = up ? hn : h2[r];
                    hst[nb][quad * 4 + r][ncol] = f2bf_u(h2[r]);
                }
                LGKM_BARRIER();
            }
            if (ch + 1 < nch) {
                WAIT_VM0();                        // chunk ch+1 landed (issued a full chunk ago)
                CONVERT();                         // own-wave fp32 region -> bf16 xst
                LGKM_BARRIER();
                if (ch + 2 < nch) DMA((ch + 2) * CH);   // keep invariant: in flight iff < nch
            }
        }
    }

#pragma unroll
    for (int r = 0; r < 2; ++r) {
        const int seg = segbase + 2 * quad + r;
        if (seg < B) out[(size_t)seg * HDIM + ncol] = h2[r];
    }
#undef DMA
#undef CONVERT
#undef CLAMPT
#undef CROW
}

extern "C" void kernel_launch(void* const* d_in, const int* in_sizes, int n_in,
                              void* d_out, int out_size, void* d_ws, size_t ws_size,
                              hipStream_t stream) {
    const float* x     = (const float*)d_in[0];
    const float* Wih   = (const float*)d_in[1];
    const float* Whh   = (const float*)d_in[2];
    const float* bih   = (const float*)d_in[3];
    const float* bhh   = (const float*)d_in[4];
    const int*   index = (const int*)d_in[5];

    const int N = in_sizes[5];
    const int B = out_size / HDIM;   // 8192

    const int nblocks = (B + 7) / 8;   // 1024 -> 4 blocks/CU, one generation
    lstm8_kernel<<<nblocks, 256, 0, stream>>>(x, Wih, Whh, bih, bhh, index,
                                              (float*)d_out, N, B);
}

// Round 9
// 264.225 us; speedup vs baseline: 1.0233x; 1.0233x over previous
//
#include <hip/hip_runtime.h>

#define MAXLEN 100
#define HDIM 64
#define CH 4                       // x-staging chunk length (steps)
#define SROW 72                    // ushorts per bf16 x step-row (144 B)
#define SPLANE (CH * SROW + 8)     // 296 ushorts per segment plane
#define HSTR 72                    // ushorts per h row (144 B)
#define L2E 1.44269504f

typedef __attribute__((ext_vector_type(8))) short bf16x8;
typedef __attribute__((ext_vector_type(4))) float f32x4;

// Step barrier: LDS-only consistency. Avoids the compiler's implicit
// s_waitcnt vmcnt(0) before s_barrier, so in-flight x prefetch (plain global
// loads into pre regs) is never drained at step barriers; the compiler
// auto-waits vmcnt before COMMIT uses the regs.
#define LGKM_BARRIER() asm volatile("s_waitcnt lgkmcnt(0)\n\ts_barrier" ::: "memory")

__device__ __forceinline__ unsigned short f2bf_u(float f) {   // RNE f32->bf16
    unsigned u = __float_as_uint(f);
    u += 0x7fffu + ((u >> 16) & 1u);
    return (unsigned short)(u >> 16);
}
__device__ __forceinline__ unsigned pk2(float a, float b) {
    return (unsigned)f2bf_u(a) | ((unsigned)f2bf_u(b) << 16);
}
__device__ __forceinline__ bf16x8 pack8(f32x4 a, f32x4 b) {
    union { unsigned u[4]; bf16x8 v; } c;
    c.u[0] = pk2(a[0], a[1]); c.u[1] = pk2(a[2], a[3]);
    c.u[2] = pk2(b[0], b[1]); c.u[3] = pk2(b[2], b[3]);
    return c.v;
}
// sigmoid(v + b) with bs = -L2E*b folded into the exp2 argument.
__device__ __forceinline__ float sig_b(float v, float bs) {
    return __builtin_amdgcn_rcpf(1.0f + __builtin_amdgcn_exp2f(fmaf(v, -L2E, bs)));
}
__device__ __forceinline__ float tanh_b(float v, float bs2) {
    return fmaf(2.0f, __builtin_amdgcn_rcpf(1.0f + __builtin_amdgcn_exp2f(fmaf(v, -2.0f * L2E, bs2))), -1.0f);
}
__device__ __forceinline__ float tanh_p(float v) {
    return fmaf(2.0f, __builtin_amdgcn_rcpf(1.0f + __builtin_amdgcn_exp2f(v * (-2.0f * L2E))), -1.0f);
}

// 1024 blocks x 256 threads; 8 segments/block; 4 waves, wave w owns hidden
// cols [16w,16w+16) for all 4 gates. Segment s -> MFMA A/C row (s>>1)*4+(s&1)
// ({0,1,4,5,8,9,12,13}): each lane's C regs 0..1 are its 2 real (seg,hid)
// bundles; garbage A rows read zeros (x: plane 8; h: odd rows zeroed once).
// Register budget at 4 waves/SIMD is 128/wave (unified VGPR+AGPR): weights 64
// + pre 8 + paired-acc peak ~12 + frags 16 + misc ~18 = ~118. No spill.
__global__ __launch_bounds__(256, 4)
void lstm8_kernel(const float* __restrict__ x,
                  const float* __restrict__ Wih,
                  const float* __restrict__ Whh,
                  const float* __restrict__ bih,
                  const float* __restrict__ bhh,
                  const int* __restrict__ index,
                  float* __restrict__ out, int N, int B) {
    const int tid  = threadIdx.x;
    const int w    = tid >> 6;
    const int lane = tid & 63;
    const int l15  = lane & 15;
    const int quad = lane >> 4;
    const int segbase = blockIdx.x * 8;
    const int ncol = w * 16 + l15;

    __shared__ __align__(16) unsigned short xst[9 * SPLANE];     // 5.3 KB (plane 8 = zeros)
    __shared__ __align__(16) unsigned short hst[2][16][HSTR];    // 4.6 KB
    __shared__ int sstart[8], slen[8];

    // --- per-block segment bounds (index sorted) ---
    if (tid < 8) {
        const int b = segbase + tid;
        int s = 0, len = 0;
        if (b < B) {
            int lo = 0, hi = N;
            while (lo < hi) { int m = (lo + hi) >> 1; if (index[m] < b) lo = m + 1; else hi = m; }
            s = lo;
            hi = N;
            while (lo < hi) { int m = (lo + hi) >> 1; if (index[m] < b + 1) lo = m + 1; else hi = m; }
            len = lo - s;
            len = len < MAXLEN ? len : MAXLEN;
        }
        sstart[tid] = s;
        slen[tid] = len;
    }
    for (int i = tid; i < 2 * 16 * HSTR / 2; i += 256) ((int*)hst)[i] = 0;
    for (int i = tid; i < SPLANE / 2; i += 256) ((int*)xst)[8 * SPLANE / 2 + i] = 0;
    __syncthreads();

    // --- weight B-fragments (register-resident) + exp-folded biases ---
    bf16x8 wi[4][2], wh[4][2];
    float bs[4];
#pragma unroll
    for (int g = 0; g < 4; ++g) {
        const int row = g * HDIM + ncol;
        const float bb = bih[row] + bhh[row];
        bs[g] = (g == 2) ? (-2.0f * L2E) * bb : (-L2E) * bb;
#pragma unroll
        for (int kt = 0; kt < 2; ++kt) {
            const f32x4* pi = (const f32x4*)(Wih + (size_t)row * HDIM + kt * 32 + quad * 8);
            const f32x4* ph = (const f32x4*)(Whh + (size_t)row * HDIM + kt * 32 + quad * 8);
            wi[g][kt] = pack8(pi[0], pi[1]);
            wh[g][kt] = pack8(ph[0], ph[1]);
        }
    }

    int len2[2];
    len2[0] = slen[2 * quad];
    len2[1] = slen[2 * quad + 1];
    int lmax = 0;
#pragma unroll
    for (int i = 0; i < 8; ++i) { int v = slen[i]; lmax = v > lmax ? v : lmax; }
    lmax = __builtin_amdgcn_readfirstlane(lmax);   // uniform -> SGPR loop bound

    // Staging role: thread covers (seg sS, chunk-step sT, 8-float col group sC).
    // 8 segs x 4 steps x 8 groups = 256 threads; pre = 8 VGPRs in flight.
    const int sS = tid >> 5, sT = (tid >> 3) & 3, sC = tid & 7;
    const int sst = sstart[sS], sln = slen[sS];

    f32x4 pre0, pre1;

    // Per-lane exact row clamp: frozen steps re-read the last valid row
    // (their gate output is discarded). Nothing dangles at kernel end
    // (plain register loads, not LDS-DMA).
#define ISSUE(t0_)                                                              \
    {                                                                           \
        int ct = (t0_) + sT;                                                    \
        ct = (sln > 0) ? (ct < sln ? ct : sln - 1) : 0;                         \
        int row = sst + ct;                                                     \
        row = row < N - 1 ? row : N - 1;                                        \
        const f32x4* p_ = (const f32x4*)(x + (size_t)row * HDIM + sC * 8);      \
        pre0 = p_[0]; pre1 = p_[1];                                             \
    }
#define COMMIT()                                                                \
    {                                                                           \
        uint4 o_;                                                               \
        o_.x = pk2(pre0[0], pre0[1]); o_.y = pk2(pre0[2], pre0[3]);             \
        o_.z = pk2(pre1[0], pre1[1]); o_.w = pk2(pre1[2], pre1[3]);             \
        *(uint4*)&xst[sS * SPLANE + sT * SROW + sC * 8] = o_;                   \
    }

    // x A-frag source plane for this lane's A-row: real seg or zero plane.
    const int xp = (l15 & 2) ? 8 : ((l15 >> 2) * 2 + (l15 & 1));
    const unsigned short* xb = &xst[xp * SPLANE + quad * 8];

    float c2[2] = {0, 0}, h2[2] = {0, 0};
    const f32x4 cz = {0.0f, 0.0f, 0.0f, 0.0f};
    const int nch = (lmax + CH - 1) / CH;

    if (nch > 0) {
        ISSUE(0);
        COMMIT();                      // compiler inserts the vmcnt wait for pre use
        LGKM_BARRIER();
        if (nch > 1) ISSUE(CH);        // chunk 1 in flight across chunk 0's steps

        for (int ch = 0; ch < nch; ++ch) {
            const int t0 = ch * CH;
#pragma unroll
            for (int tt = 0; tt < CH; ++tt) {
                const int t = t0 + tt;          // parity(t) == parity(tt), CH even
                const int pb = tt & 1, nb = pb ^ 1;

                const unsigned short* xr = xb + tt * SROW;
                bf16x8 xa0 = *(const bf16x8*)(xr);
                bf16x8 xa1 = *(const bf16x8*)(xr + 32);
                const unsigned short* hr = &hst[pb][l15][quad * 8];
                bf16x8 ha0 = *(const bf16x8*)(hr);
                bf16x8 ha1 = *(const bf16x8*)(hr + 32);

                // Gate pair {i,f}: two 4-deep MFMA chains, then extract scalars
                // (frees the f32x4s); their transcendentals overlap pair {g,o}.
                float gi0, gi1, gf0, gf1, gg0, gg1, go0, go1;
                {
                    f32x4 a0 = __builtin_amdgcn_mfma_f32_16x16x32_bf16(xa0, wi[0][0], cz, 0, 0, 0);
                    a0 = __builtin_amdgcn_mfma_f32_16x16x32_bf16(xa1, wi[0][1], a0, 0, 0, 0);
                    a0 = __builtin_amdgcn_mfma_f32_16x16x32_bf16(ha0, wh[0][0], a0, 0, 0, 0);
                    a0 = __builtin_amdgcn_mfma_f32_16x16x32_bf16(ha1, wh[0][1], a0, 0, 0, 0);
                    f32x4 a1 = __builtin_amdgcn_mfma_f32_16x16x32_bf16(xa0, wi[1][0], cz, 0, 0, 0);
                    a1 = __builtin_amdgcn_mfma_f32_16x16x32_bf16(xa1, wi[1][1], a1, 0, 0, 0);
                    a1 = __builtin_amdgcn_mfma_f32_16x16x32_bf16(ha0, wh[1][0], a1, 0, 0, 0);
                    a1 = __builtin_amdgcn_mfma_f32_16x16x32_bf16(ha1, wh[1][1], a1, 0, 0, 0);
                    gi0 = sig_b(a0[0], bs[0]); gi1 = sig_b(a0[1], bs[0]);
                    gf0 = sig_b(a1[0], bs[1]); gf1 = sig_b(a1[1], bs[1]);
                }
                {
                    f32x4 a2 = __builtin_amdgcn_mfma_f32_16x16x32_bf16(xa0, wi[2][0], cz, 0, 0, 0);
                    a2 = __builtin_amdgcn_mfma_f32_16x16x32_bf16(xa1, wi[2][1], a2, 0, 0, 0);
                    a2 = __builtin_amdgcn_mfma_f32_16x16x32_bf16(ha0, wh[2][0], a2, 0, 0, 0);
                    a2 = __builtin_amdgcn_mfma_f32_16x16x32_bf16(ha1, wh[2][1], a2, 0, 0, 0);
                    f32x4 a3 = __builtin_amdgcn_mfma_f32_16x16x32_bf16(xa0, wi[3][0], cz, 0, 0, 0);
                    a3 = __builtin_amdgcn_mfma_f32_16x16x32_bf16(xa1, wi[3][1], a3, 0, 0, 0);
                    a3 = __builtin_amdgcn_mfma_f32_16x16x32_bf16(ha0, wh[3][0], a3, 0, 0, 0);
                    a3 = __builtin_amdgcn_mfma_f32_16x16x32_bf16(ha1, wh[3][1], a3, 0, 0, 0);
                    gg0 = tanh_b(a2[0], bs[2]); gg1 = tanh_b(a2[1], bs[2]);
                    go0 = sig_b (a3[0], bs[3]); go1 = sig_b (a3[1], bs[3]);
                }

                // State update: 2 real bundles/lane (segs 2q, 2q+1).
                {
                    float cn = fmaf(gf0, c2[0], gi0 * gg0);
                    float hn = go0 * tanh_p(cn);
                    const bool up = t < len2[0];
                    c2[0] = up ? cn : c2[0];
                    h2[0] = up ? hn : h2[0];
                    hst[nb][quad * 4 + 0][ncol] = f2bf_u(h2[0]);
                }
                {
                    float cn = fmaf(gf1, c2[1], gi1 * gg1);
                    float hn = go1 * tanh_p(cn);
                    const bool up = t < len2[1];
                    c2[1] = up ? cn : c2[1];
                    h2[1] = up ? hn : h2[1];
                    hst[nb][quad * 4 + 1][ncol] = f2bf_u(h2[1]);
                }
                LGKM_BARRIER();
            }
            if (ch + 1 < nch) {
                COMMIT();                          // chunk ch+1 (vmcnt auto-waited)
                LGKM_BARRIER();
                if (ch + 2 < nch) ISSUE((ch + 2) * CH);
            }
        }
    }

#pragma unroll
    for (int r = 0; r < 2; ++r) {
        const int seg = segbase + 2 * quad + r;
        if (seg < B) out[(size_t)seg * HDIM + ncol] = h2[r];
    }
#undef ISSUE
#undef COMMIT
}

extern "C" void kernel_launch(void* const* d_in, const int* in_sizes, int n_in,
                              void* d_out, int out_size, void* d_ws, size_t ws_size,
                              hipStream_t stream) {
    const float* x     = (const float*)d_in[0];
    const float* Wih   = (const float*)d_in[1];
    const float* Whh   = (const float*)d_in[2];
    const float* bih   = (const float*)d_in[3];
    const float* bhh   = (const float*)d_in[4];
    const int*   index = (const int*)d_in[5];

    const int N = in_sizes[5];
    const int B = out_size / HDIM;   // 8192

    const int nblocks = (B + 7) / 8;   // 1024 -> 4 blocks/CU, one generation
    lstm8_kernel<<<nblocks, 256, 0, stream>>>(x, Wih, Whh, bih, bhh, index,
                                              (float*)d_out, N, B);
}

// Round 10
// 258.457 us; speedup vs baseline: 1.0462x; 1.0223x over previous
//
#include <hip/hip_runtime.h>

#define MAXLEN 100
#define HDIM 64
#define CH 8                       // x-staging chunk length (steps)
#define NSEG 12                    // segments per block (12 real rows of 16)
#define SROW 72                    // ushorts per bf16 x step-row (144 B)
#define SPLANE (CH * SROW + 8)     // 584 ushorts per segment plane
#define HSTR 72                    // ushorts per h row (144 B)
#define L2E 1.44269504f

typedef __attribute__((ext_vector_type(8))) short bf16x8;
typedef __attribute__((ext_vector_type(4))) float f32x4;

// Step barrier: LDS-only consistency (no implicit vmcnt(0) drain), so the
// chunk-ahead x prefetch stays in flight across all 8 step barriers.
#define LGKM_BARRIER() asm volatile("s_waitcnt lgkmcnt(0)\n\ts_barrier" ::: "memory")

__device__ __forceinline__ unsigned short f2bf_u(float f) {   // RNE f32->bf16
    unsigned u = __float_as_uint(f);
    u += 0x7fffu + ((u >> 16) & 1u);
    return (unsigned short)(u >> 16);
}
__device__ __forceinline__ unsigned pk2(float a, float b) {
    return (unsigned)f2bf_u(a) | ((unsigned)f2bf_u(b) << 16);
}
__device__ __forceinline__ bf16x8 pack8(f32x4 a, f32x4 b) {
    union { unsigned u[4]; bf16x8 v; } c;
    c.u[0] = pk2(a[0], a[1]); c.u[1] = pk2(a[2], a[3]);
    c.u[2] = pk2(b[0], b[1]); c.u[3] = pk2(b[2], b[3]);
    return c.v;
}
// sigmoid(v + b) with bs = -L2E*b folded into the exp2 argument.
__device__ __forceinline__ float sig_b(float v, float bs) {
    return __builtin_amdgcn_rcpf(1.0f + __builtin_amdgcn_exp2f(fmaf(v, -L2E, bs)));
}
__device__ __forceinline__ float tanh_b(float v, float bs2) {
    return fmaf(2.0f, __builtin_amdgcn_rcpf(1.0f + __builtin_amdgcn_exp2f(fmaf(v, -2.0f * L2E, bs2))), -1.0f);
}
__device__ __forceinline__ float tanh_p(float v) {
    return fmaf(2.0f, __builtin_amdgcn_rcpf(1.0f + __builtin_amdgcn_exp2f(v * (-2.0f * L2E))), -1.0f);
}

// 683 blocks x 256 threads; 12 segments/block; 4 waves, wave w owns hidden
// cols [16w,16w+16) for all 4 gates. Segment s -> MFMA A/C row (s/3)*4+(s%3):
// each lane's C regs 0..2 are its 3 real (seg,hid) bundles. MFMA C-row
// independence (C[m][.] depends only on A[m][.]) means garbage A rows
// {3,7,11,15} need no zeroing -- they pollute only the unread C reg 3.
// Designed for 3 waves/SIMD (launch_bounds(256,3) -> 170-reg budget, no
// spill); grid 683 <= 3/CU x 256 -> ONE resident generation (this was the
// hidden 2x makespan loss in R8/R9's 1024-block 3-resident runs).
__global__ __launch_bounds__(256, 3)
void lstm12_kernel(const float* __restrict__ x,
                   const float* __restrict__ Wih,
                   const float* __restrict__ Whh,
                   const float* __restrict__ bih,
                   const float* __restrict__ bhh,
                   const int* __restrict__ index,
                   float* __restrict__ out, int N, int B) {
    const int tid  = threadIdx.x;
    const int w    = tid >> 6;
    const int lane = tid & 63;
    const int l15  = lane & 15;
    const int quad = lane >> 4;
    const int segbase = blockIdx.x * NSEG;
    const int ncol = w * 16 + l15;

    __shared__ __align__(16) unsigned short xst[NSEG * SPLANE];  // 14.0 KB
    __shared__ __align__(16) unsigned short hst[2][16][HSTR];    //  4.6 KB
    __shared__ int sstart[NSEG], slen[NSEG];

    // --- per-block segment bounds (index sorted) ---
    if (tid < NSEG) {
        const int b = segbase + tid;
        int s = 0, len = 0;
        if (b < B) {
            int lo = 0, hi = N;
            while (lo < hi) { int m = (lo + hi) >> 1; if (index[m] < b) lo = m + 1; else hi = m; }
            s = lo;
            hi = N;
            while (lo < hi) { int m = (lo + hi) >> 1; if (index[m] < b + 1) lo = m + 1; else hi = m; }
            len = lo - s;
            len = len < MAXLEN ? len : MAXLEN;
        }
        sstart[tid] = s;
        slen[tid] = len;
    }
    for (int i = tid; i < 2 * 16 * HSTR / 2; i += 256) ((int*)hst)[i] = 0;
    __syncthreads();

    // --- weight B-fragments (register-resident) + exp-folded biases ---
    bf16x8 wi[4][2], wh[4][2];
    float bs[4];
#pragma unroll
    for (int g = 0; g < 4; ++g) {
        const int row = g * HDIM + ncol;
        const float bb = bih[row] + bhh[row];
        bs[g] = (g == 2) ? (-2.0f * L2E) * bb : (-L2E) * bb;
#pragma unroll
        for (int kt = 0; kt < 2; ++kt) {
            const f32x4* pi = (const f32x4*)(Wih + (size_t)row * HDIM + kt * 32 + quad * 8);
            const f32x4* ph = (const f32x4*)(Whh + (size_t)row * HDIM + kt * 32 + quad * 8);
            wi[g][kt] = pack8(pi[0], pi[1]);
            wh[g][kt] = pack8(ph[0], ph[1]);
        }
    }

    // Per-lane gate-math metadata: segs quad*3 + r, r in 0..2.
    int len3[3];
#pragma unroll
    for (int r = 0; r < 3; ++r) len3[r] = slen[quad * 3 + r];
    int lmax = 0;
#pragma unroll
    for (int i = 0; i < NSEG; ++i) { int v = slen[i]; lmax = v > lmax ? v : lmax; }
    lmax = __builtin_amdgcn_readfirstlane(lmax);

    // Staging roles: 12 segs x 8 steps x 8 col-groups(8 floats) = 768 units,
    // 3 per thread (k=0..2, seg = (tid>>6) + 4k; step/colgrp shared).
    const int ustep = (tid >> 3) & 7, ugrp = tid & 7;
    const int us0 = tid >> 6;
    int sst3[3], sln3[3];
#pragma unroll
    for (int k = 0; k < 3; ++k) { sst3[k] = sstart[us0 + 4 * k]; sln3[k] = slen[us0 + 4 * k]; }

    f32x4 pre[3][2];   // 24 VGPRs in flight per thread

#define ISSUE(t0_)                                                              \
    {                                                                           \
        _Pragma("unroll")                                                       \
        for (int k_ = 0; k_ < 3; ++k_) {                                        \
            int ct = (t0_) + ustep;                                             \
            ct = (sln3[k_] > 0) ? (ct < sln3[k_] ? ct : sln3[k_] - 1) : 0;      \
            int row = sst3[k_] + ct;                                            \
            row = row < N - 1 ? row : N - 1;                                    \
            const f32x4* p_ = (const f32x4*)(x + (size_t)row * HDIM + ugrp * 8);\
            pre[k_][0] = p_[0]; pre[k_][1] = p_[1];                             \
        }                                                                       \
    }
#define COMMIT()                                                                \
    {                                                                           \
        _Pragma("unroll")                                                       \
        for (int k_ = 0; k_ < 3; ++k_) {                                        \
            uint4 o_;                                                           \
            o_.x = pk2(pre[k_][0][0], pre[k_][0][1]);                           \
            o_.y = pk2(pre[k_][0][2], pre[k_][0][3]);                           \
            o_.z = pk2(pre[k_][1][0], pre[k_][1][1]);                           \
            o_.w = pk2(pre[k_][1][2], pre[k_][1][3]);                           \
            *(uint4*)&xst[(us0 + 4 * k_) * SPLANE + ustep * SROW + ugrp * 8] = o_; \
        }                                                                       \
    }

    // x A-frag source plane for this lane's A-row m=l15: real seg
    // (m>>2)*3 + (m&3) for m&3<3; garbage rows (m&3==3) alias the previous
    // plane (same-address LDS broadcast with the m&3==2 lane -> free).
    const int m3 = l15 & 3;
    const int xp = (l15 >> 2) * 3 + (m3 < 2 ? m3 : 2);
    const unsigned short* xb = &xst[xp * SPLANE + quad * 8];

    float c3[3] = {0, 0, 0}, h3[3] = {0, 0, 0};
    const f32x4 cz = {0.0f, 0.0f, 0.0f, 0.0f};
    const int nch = (lmax + CH - 1) / CH;

    if (nch > 0) {
        ISSUE(0);
        COMMIT();                      // compiler auto-waits vmcnt for pre use
        LGKM_BARRIER();
        if (nch > 1) ISSUE(CH);        // chunk 1 in flight across chunk 0's steps

        for (int ch = 0; ch < nch; ++ch) {
            const int t0 = ch * CH;
#pragma unroll
            for (int tt = 0; tt < CH; ++tt) {
                const int t = t0 + tt;          // parity(t) == parity(tt), CH even
                const int pb = tt & 1, nb = pb ^ 1;

                const unsigned short* xr = xb + tt * SROW;
                bf16x8 xa0 = *(const bf16x8*)(xr);
                bf16x8 xa1 = *(const bf16x8*)(xr + 32);
                const unsigned short* hr = &hst[pb][l15][quad * 8];
                bf16x8 ha0 = *(const bf16x8*)(hr);
                bf16x8 ha1 = *(const bf16x8*)(hr + 32);

                f32x4 acc[4];
#pragma unroll
                for (int g = 0; g < 4; ++g) {
                    f32x4 a = __builtin_amdgcn_mfma_f32_16x16x32_bf16(xa0, wi[g][0], cz, 0, 0, 0);
                    a = __builtin_amdgcn_mfma_f32_16x16x32_bf16(xa1, wi[g][1], a, 0, 0, 0);
                    a = __builtin_amdgcn_mfma_f32_16x16x32_bf16(ha0, wh[g][0], a, 0, 0, 0);
                    a = __builtin_amdgcn_mfma_f32_16x16x32_bf16(ha1, wh[g][1], a, 0, 0, 0);
                    acc[g] = a;
                }

                // Gate math: 3 real bundles/lane (C regs 0..2 = segs 3q..3q+2).
#pragma unroll
                for (int r = 0; r < 3; ++r) {
                    float gi = sig_b (acc[0][r], bs[0]);
                    float gf = sig_b (acc[1][r], bs[1]);
                    float gg = tanh_b(acc[2][r], bs[2]);
                    float go = sig_b (acc[3][r], bs[3]);
                    float cn = fmaf(gf, c3[r], gi * gg);
                    float hn = go * tanh_p(cn);
                    const bool up = t < len3[r];
                    c3[r] = up ? cn : c3[r];
                    h3[r] = up ? hn : h3[r];
                    hst[nb][quad * 4 + r][ncol] = f2bf_u(h3[r]);
                }
                LGKM_BARRIER();
            }
            if (ch + 1 < nch) {
                COMMIT();                          // chunk ch+1 (vmcnt auto-waited)
                LGKM_BARRIER();
                if (ch + 2 < nch) ISSUE((ch + 2) * CH);
            }
        }
    }

#pragma unroll
    for (int r = 0; r < 3; ++r) {
        const int seg = segbase + quad * 3 + r;
        if (seg < B) out[(size_t)seg * HDIM + ncol] = h3[r];
    }
#undef ISSUE
#undef COMMIT
}

extern "C" void kernel_launch(void* const* d_in, const int* in_sizes, int n_in,
                              void* d_out, int out_size, void* d_ws, size_t ws_size,
                              hipStream_t stream) {
    const float* x     = (const float*)d_in[0];
    const float* Wih   = (const float*)d_in[1];
    const float* Whh   = (const float*)d_in[2];
    const float* bih   = (const float*)d_in[3];
    const float* bhh   = (const float*)d_in[4];
    const int*   index = (const int*)d_in[5];

    const int N = in_sizes[5];
    const int B = out_size / HDIM;   // 8192

    const int nblocks = (B + NSEG - 1) / NSEG;   // 683 -> one resident generation
    lstm12_kernel<<<nblocks, 256, 0, stream>>>(x, Wih, Whh, bih, bhh, index,
                                               (float*)d_out, N, B);
}

// Round 11
// 250.079 us; speedup vs baseline: 1.0812x; 1.0335x over previous
//
#include <hip/hip_runtime.h>

#define MAXLEN 100
#define HDIM 64
#define CH 4                       // x-staging chunk length (steps)
#define NSEG 12                    // segments per block (12 real rows of 16)
#define SROW 72                    // ushorts per bf16 x step-row (144 B)
#define SPLANE (CH * SROW + 8)     // 296 ushorts per segment plane
#define HSTR 72                    // ushorts per h row (144 B)
#define L2E 1.44269504f

typedef __attribute__((ext_vector_type(8))) short bf16x8;
typedef __attribute__((ext_vector_type(4))) float f32x4;

// Step barrier: LDS-only consistency (no implicit vmcnt(0) drain), so the
// chunk-ahead x prefetch stays in flight across all step barriers.
#define LGKM_BARRIER() asm volatile("s_waitcnt lgkmcnt(0)\n\ts_barrier" ::: "memory")

__device__ __forceinline__ unsigned short f2bf_u(float f) {   // RNE f32->bf16
    unsigned u = __float_as_uint(f);
    u += 0x7fffu + ((u >> 16) & 1u);
    return (unsigned short)(u >> 16);
}
__device__ __forceinline__ unsigned pk2(float a, float b) {
    return (unsigned)f2bf_u(a) | ((unsigned)f2bf_u(b) << 16);
}
__device__ __forceinline__ bf16x8 pack8(f32x4 a, f32x4 b) {
    union { unsigned u[4]; bf16x8 v; } c;
    c.u[0] = pk2(a[0], a[1]); c.u[1] = pk2(a[2], a[3]);
    c.u[2] = pk2(b[0], b[1]); c.u[3] = pk2(b[2], b[3]);
    return c.v;
}
// sigmoid(v + b) with bs = -L2E*b folded into the exp2 argument.
__device__ __forceinline__ float sig_b(float v, float bs) {
    return __builtin_amdgcn_rcpf(1.0f + __builtin_amdgcn_exp2f(fmaf(v, -L2E, bs)));
}
__device__ __forceinline__ float tanh_b(float v, float bs2) {
    return fmaf(2.0f, __builtin_amdgcn_rcpf(1.0f + __builtin_amdgcn_exp2f(fmaf(v, -2.0f * L2E, bs2))), -1.0f);
}
__device__ __forceinline__ float tanh_p(float v) {
    return fmaf(2.0f, __builtin_amdgcn_rcpf(1.0f + __builtin_amdgcn_exp2f(v * (-2.0f * L2E))), -1.0f);
}

// 683 blocks x 256 threads; 12 segments/block; 4 waves, wave w owns hidden
// cols [16w,16w+16) for all 4 gates. Segment s -> MFMA A/C row (s/3)*4+(s%3);
// each lane's C regs 0..2 are its 3 real (seg,hid) bundles; garbage A rows
// need no zeroing (C-row independence).
// KEY CHANGE vs R10: the per-step MFMA chain is split. accx[g] = x_t @ Wih
// (2-deep, h-independent) is computed in the PREVIOUS step's trans shadow;
// the serial step seeds the h-chain with it: acc = mfma(ha1,wh1,
// mfma(ha0,wh0,accx)). Critical path per step ~halves (4-deep -> 2-deep
// MFMA + only the h-dependent work between barriers).
__global__ __launch_bounds__(256, 3)
void lstm12_kernel(const float* __restrict__ x,
                   const float* __restrict__ Wih,
                   const float* __restrict__ Whh,
                   const float* __restrict__ bih,
                   const float* __restrict__ bhh,
                   const int* __restrict__ index,
                   float* __restrict__ out, int N, int B) {
    const int tid  = threadIdx.x;
    const int w    = tid >> 6;
    const int lane = tid & 63;
    const int l15  = lane & 15;
    const int quad = lane >> 4;
    const int segbase = blockIdx.x * NSEG;
    const int ncol = w * 16 + l15;

    __shared__ __align__(16) unsigned short xst[NSEG * SPLANE];  // 7.1 KB
    __shared__ __align__(16) unsigned short hst[2][16][HSTR];    // 4.6 KB
    __shared__ int sstart[NSEG], slen[NSEG];

    // --- per-block segment bounds (index sorted) ---
    if (tid < NSEG) {
        const int b = segbase + tid;
        int s = 0, len = 0;
        if (b < B) {
            int lo = 0, hi = N;
            while (lo < hi) { int m = (lo + hi) >> 1; if (index[m] < b) lo = m + 1; else hi = m; }
            s = lo;
            hi = N;
            while (lo < hi) { int m = (lo + hi) >> 1; if (index[m] < b + 1) lo = m + 1; else hi = m; }
            len = lo - s;
            len = len < MAXLEN ? len : MAXLEN;
        }
        sstart[tid] = s;
        slen[tid] = len;
    }
    for (int i = tid; i < 2 * 16 * HSTR / 2; i += 256) ((int*)hst)[i] = 0;
    __syncthreads();

    // --- weight B-fragments (register-resident) + exp-folded biases ---
    bf16x8 wi[4][2], wh[4][2];
    float bs[4];
#pragma unroll
    for (int g = 0; g < 4; ++g) {
        const int row = g * HDIM + ncol;
        const float bb = bih[row] + bhh[row];
        bs[g] = (g == 2) ? (-2.0f * L2E) * bb : (-L2E) * bb;
#pragma unroll
        for (int kt = 0; kt < 2; ++kt) {
            const f32x4* pi = (const f32x4*)(Wih + (size_t)row * HDIM + kt * 32 + quad * 8);
            const f32x4* ph = (const f32x4*)(Whh + (size_t)row * HDIM + kt * 32 + quad * 8);
            wi[g][kt] = pack8(pi[0], pi[1]);
            wh[g][kt] = pack8(ph[0], ph[1]);
        }
    }

    // Per-lane gate-math metadata: segs quad*3 + r, r in 0..2.
    int len3[3];
#pragma unroll
    for (int r = 0; r < 3; ++r) len3[r] = slen[quad * 3 + r];
    int lmax = 0;
#pragma unroll
    for (int i = 0; i < NSEG; ++i) { int v = slen[i]; lmax = v > lmax ? v : lmax; }
    lmax = __builtin_amdgcn_readfirstlane(lmax);

    // Staging roles: 12 segs x 4 steps x 4 col-groups(16 floats) = 192 units;
    // waves 0..2 stage (tid < 192), wave 3 idle in staging. pre = 16 VGPRs.
    const int sS = tid >> 4, sT = (tid >> 2) & 3, sC = tid & 3;   // valid for tid<192
    const int sst = (tid < 192) ? sstart[sS] : 0;
    const int sln = (tid < 192) ? slen[sS] : 0;

    f32x4 pre[4];

#define ISSUE(t0_)                                                              \
    if (w < 3) {                                                                \
        int ct = (t0_) + sT;                                                    \
        ct = (sln > 0) ? (ct < sln ? ct : sln - 1) : 0;                         \
        int row = sst + ct;                                                     \
        row = row < N - 1 ? row : N - 1;                                        \
        const f32x4* p_ = (const f32x4*)(x + (size_t)row * HDIM + sC * 16);     \
        pre[0] = p_[0]; pre[1] = p_[1]; pre[2] = p_[2]; pre[3] = p_[3];         \
    }
#define COMMIT()                                                                \
    if (w < 3) {                                                                \
        uint4 o1, o2;                                                           \
        o1.x = pk2(pre[0][0], pre[0][1]); o1.y = pk2(pre[0][2], pre[0][3]);     \
        o1.z = pk2(pre[1][0], pre[1][1]); o1.w = pk2(pre[1][2], pre[1][3]);     \
        o2.x = pk2(pre[2][0], pre[2][1]); o2.y = pk2(pre[2][2], pre[2][3]);     \
        o2.z = pk2(pre[3][0], pre[3][1]); o2.w = pk2(pre[3][2], pre[3][3]);     \
        unsigned short* d_ = &xst[sS * SPLANE + sT * SROW + sC * 16];           \
        *(uint4*)d_ = o1; *(uint4*)(d_ + 8) = o2;                               \
    }

    // x A-frag source plane for this lane's A-row m=l15: real seg
    // (m>>2)*3 + min(m&3,2); garbage rows alias a real plane (broadcast, free).
    const int m3 = l15 & 3;
    const int xp = (l15 >> 2) * 3 + (m3 < 2 ? m3 : 2);
    const unsigned short* xb = &xst[xp * SPLANE + quad * 8];

    // accx[g] = x_t @ Wih for the upcoming step (h-independent 2-deep chain).
    f32x4 accx[4];
#define ACCX(tt_)                                                               \
    {                                                                           \
        const unsigned short* xr_ = xb + (tt_) * SROW;                          \
        bf16x8 xa0_ = *(const bf16x8*)(xr_);                                    \
        bf16x8 xa1_ = *(const bf16x8*)(xr_ + 32);                               \
        _Pragma("unroll")                                                       \
        for (int g_ = 0; g_ < 4; ++g_) {                                        \
            f32x4 a_ = __builtin_amdgcn_mfma_f32_16x16x32_bf16(xa0_, wi[g_][0], cz, 0, 0, 0); \
            accx[g_] = __builtin_amdgcn_mfma_f32_16x16x32_bf16(xa1_, wi[g_][1], a_, 0, 0, 0); \
        }                                                                       \
    }

    float c3[3] = {0, 0, 0}, h3[3] = {0, 0, 0};
    const f32x4 cz = {0.0f, 0.0f, 0.0f, 0.0f};
    const int nch = (lmax + CH - 1) / CH;

    if (nch > 0) {
        ISSUE(0);
        COMMIT();                      // compiler auto-waits vmcnt for pre use
        LGKM_BARRIER();
        ACCX(0);                       // x-part of step 0
        if (nch > 1) ISSUE(CH);        // chunk 1 in flight across chunk 0's steps

        for (int ch = 0; ch < nch; ++ch) {
            const int t0 = ch * CH;
#pragma unroll
            for (int tt = 0; tt < CH; ++tt) {
                const int t = t0 + tt;          // parity(t) == parity(tt), CH even
                const int pb = tt & 1, nb = pb ^ 1;

                // h-dependent half: 2-deep chain seeded by accx.
                const unsigned short* hr = &hst[pb][l15][quad * 8];
                bf16x8 ha0 = *(const bf16x8*)(hr);
                bf16x8 ha1 = *(const bf16x8*)(hr + 32);

                f32x4 acc[4];
#pragma unroll
                for (int g = 0; g < 4; ++g) {
                    f32x4 a = __builtin_amdgcn_mfma_f32_16x16x32_bf16(ha0, wh[g][0], accx[g], 0, 0, 0);
                    acc[g] = __builtin_amdgcn_mfma_f32_16x16x32_bf16(ha1, wh[g][1], a, 0, 0, 0);
                }

                // x-part of the NEXT step (independent of h): fills the
                // MFMA pipe while this step's gate trans runs.
                if (tt + 1 < CH) ACCX(tt + 1);

                // Gate math: 3 real bundles/lane (C regs 0..2 = segs 3q..3q+2).
#pragma unroll
                for (int r = 0; r < 3; ++r) {
                    float gi = sig_b (acc[0][r], bs[0]);
                    float gf = sig_b (acc[1][r], bs[1]);
                    float gg = tanh_b(acc[2][r], bs[2]);
                    float go = sig_b (acc[3][r], bs[3]);
                    float cn = fmaf(gf, c3[r], gi * gg);
                    float hn = go * tanh_p(cn);
                    const bool up = t < len3[r];
                    c3[r] = up ? cn : c3[r];
                    h3[r] = up ? hn : h3[r];
                    hst[nb][quad * 4 + r][ncol] = f2bf_u(h3[r]);
                }
                LGKM_BARRIER();
            }
            if (ch + 1 < nch) {
                COMMIT();                          // chunk ch+1 (vmcnt auto-waited)
                LGKM_BARRIER();
                ACCX(0);                           // x-part of next chunk's step 0
                if (ch + 2 < nch) ISSUE((ch + 2) * CH);
            }
        }
    }

#pragma unroll
    for (int r = 0; r < 3; ++r) {
        const int seg = segbase + quad * 3 + r;
        if (seg < B) out[(size_t)seg * HDIM + ncol] = h3[r];
    }
#undef ISSUE
#undef COMMIT
#undef ACCX
}

extern "C" void kernel_launch(void* const* d_in, const int* in_sizes, int n_in,
                              void* d_out, int out_size, void* d_ws, size_t ws_size,
                              hipStream_t stream) {
    const float* x     = (const float*)d_in[0];
    const float* Wih   = (const float*)d_in[1];
    const float* Whh   = (const float*)d_in[2];
    const float* bih   = (const float*)d_in[3];
    const float* bhh   = (const float*)d_in[4];
    const int*   index = (const int*)d_in[5];

    const int N = in_sizes[5];
    const int B = out_size / HDIM;   // 8192

    const int nblocks = (B + NSEG - 1) / NSEG;   // 683
    lstm12_kernel<<<nblocks, 256, 0, stream>>>(x, Wih, Whh, bih, bhh, index,
                                               (float*)d_out, N, B);
}